// Round 11
// baseline (176.231 us; speedup 1.0000x reference)
//
#include <hip/hip_runtime.h>

#define NHID   512
#define NCLS   250
#define CHUNK  200
#define NTOK   2048
#define NOUT   450
#define NPAN   13              // ceil(CHUNK/16) 16-row word panels per class
#define NWB    (NCLS * NPAN)   // 3250 p_words blocks
#define NSTR   256             // L3-warming streamer blocks (dispatched FIRST)
#define NCB    256             // p_class blocks
#define NBLK   (NSTR + NCB + NWB)   // 3762
#define NTHR   64              // 1 wave per block
#define MAXTOK 64

typedef __attribute__((ext_vector_type(8))) short bf16x8;
typedef __attribute__((ext_vector_type(4))) float f32x4;

#define MFMA(a, b, c) __builtin_amdgcn_mfma_f32_16x16x32_bf16((a), (b), (c), 0, 0, 0)

// float offset of k-step s within a swizzled LDS row (halves of 256 floats)
#define BOFF(s) ((((s) >> 3) * 256) + (((s) & 7) * 32))

__device__ __forceinline__ unsigned hpack(unsigned a, unsigned b) {
    return __builtin_amdgcn_perm(a, b, 0x07060302u);
}

// fp32x8 -> hi/lo split bf16x8 (truncate hi; lo = truncate(exact residual))
__device__ __forceinline__ void cvt8(float4 va, float4 vb, bf16x8& h, bf16x8& l) {
    unsigned u0 = __float_as_uint(va.x), u1 = __float_as_uint(va.y);
    unsigned u2 = __float_as_uint(va.z), u3 = __float_as_uint(va.w);
    unsigned u4 = __float_as_uint(vb.x), u5 = __float_as_uint(vb.y);
    unsigned u6 = __float_as_uint(vb.z), u7 = __float_as_uint(vb.w);
    union { unsigned w[4]; bf16x8 v; } H, L;
    H.w[0] = hpack(u1, u0); H.w[1] = hpack(u3, u2);
    H.w[2] = hpack(u5, u4); H.w[3] = hpack(u7, u6);
    float r0 = va.x - __uint_as_float(u0 & 0xffff0000u);
    float r1 = va.y - __uint_as_float(u1 & 0xffff0000u);
    float r2 = va.z - __uint_as_float(u2 & 0xffff0000u);
    float r3 = va.w - __uint_as_float(u3 & 0xffff0000u);
    float r4 = vb.x - __uint_as_float(u4 & 0xffff0000u);
    float r5 = vb.y - __uint_as_float(u5 & 0xffff0000u);
    float r6 = vb.z - __uint_as_float(u6 & 0xffff0000u);
    float r7 = vb.w - __uint_as_float(u7 & 0xffff0000u);
    L.w[0] = hpack(__float_as_uint(r1), __float_as_uint(r0));
    L.w[1] = hpack(__float_as_uint(r3), __float_as_uint(r2));
    L.w[2] = hpack(__float_as_uint(r5), __float_as_uint(r4));
    L.w[3] = hpack(__float_as_uint(r7), __float_as_uint(r6));
    h = H.v; l = L.v;
}

// async 16B/lane global->LDS (wave-uniform LDS base; HW adds lane*16;
// GLOBAL source address is per-lane -> source-side swizzle is legal)
__device__ __forceinline__ void async16(const float* g, float* lds_base) {
    __builtin_amdgcn_global_load_lds(
        (const __attribute__((address_space(1))) unsigned*)g,
        (__attribute__((address_space(3))) unsigned*)lds_base, 16, 0, 0);
}

__device__ __forceinline__ void lds_fence_wave() {
    __builtin_amdgcn_wave_barrier();
    asm volatile("s_waitcnt lgkmcnt(0)" ::: "memory");
    __builtin_amdgcn_wave_barrier();
}

__global__ __launch_bounds__(NTHR)
void cbd_fused(const float* __restrict__ x,  const float* __restrict__ Wc,
               const float* __restrict__ bc, const float* __restrict__ Ww,
               const float* __restrict__ bw, const int* __restrict__ cls_idx,
               float* __restrict__ out)
{
    __shared__ float Bbuf[16 * 512];   // 32 KB swizzled B panel (whole block tile)
    __shared__ int   toktmp[MAXTOK];

    const int bid  = blockIdx.x;
    const int lane = threadIdx.x;     // 64-thread block = one wave
    const int n    = lane & 15;       // fragment row slot
    const int q    = lane >> 4;       // k-quad

    if (bid < NSTR) {
        // ============ L3-warming streamers: pure fetch, no consumption =======
        // XCD sx's 32 streamer waves sweep the SAME Ww region its compute
        // blocks will consume (forward order). 16-deep unconsumed dwordx4
        // bursts per iteration: copy-class MLP, unthrottled by compute.
        const int sx = bid & 7;          // XCD (dispatch round-robin)
        const int sj = bid >> 3;         // 0..31 within XCD
        const int B0 = (sx < 2) ? sx * 407 : 2 * 407 + (sx - 2) * 406;
        const int B1 = B0 + ((sx < 2) ? 407 : 406);
        int c0 = B0 / NPAN;
        int c1 = (B1 + NPAN - 1) / NPAN; if (c1 > NCLS) c1 = NCLS;
        const f32x4* gb = (const f32x4*)(Ww + (size_t)c0 * CHUNK * NHID);
        const int nf4 = (c1 - c0) * (CHUNK * NHID / 4);
        const int stride = 2048 * 16;    // 2048 threads/XCD x 16 f4 each
        for (int i = (sj * 64 + lane) * 16; i + 15 < nf4; i += stride) {
            f32x4 a0 = gb[i+0],  a1 = gb[i+1],  a2 = gb[i+2],  a3 = gb[i+3];
            f32x4 a4 = gb[i+4],  a5 = gb[i+5],  a6 = gb[i+6],  a7 = gb[i+7];
            f32x4 a8 = gb[i+8],  a9 = gb[i+9],  aA = gb[i+10], aB = gb[i+11];
            f32x4 aC = gb[i+12], aD = gb[i+13], aE = gb[i+14], aF = gb[i+15];
            asm volatile("" :: "v"(a0),"v"(a1),"v"(a2),"v"(a3),
                               "v"(a4),"v"(a5),"v"(a6),"v"(a7),
                               "v"(a8),"v"(a9),"v"(aA),"v"(aB),
                               "v"(aC),"v"(aD),"v"(aE),"v"(aF));
        }
        return;
    }

    if (bid < NSTR + NCB) {
        // ======== p_class tiles (L2-hot Wc), 2-deep register pipeline ========
        const int pcb = bid - NSTR;
        const int mt = pcb >> 1, hn = pcb & 1;
        const float* ap = x + (size_t)(mt * 16 + n) * NHID + q * 8;
        #pragma unroll
        for (int g4 = 0; g4 < 2; ++g4) {
            const float* bp[4]; float bias[4]; int col[4]; bool rv[4];
            #pragma unroll
            for (int k = 0; k < 4; ++k) {
                int r = (hn * 8 + g4 * 4 + k) * 16 + n;
                rv[k] = r < NCLS;
                int rc = rv[k] ? r : NCLS - 1;
                bp[k]   = Wc + (size_t)rc * NHID + q * 8;
                bias[k] = bc[rc];
                col[k]  = rc;
            }
            f32x4 acc[4] = {{0,0,0,0},{0,0,0,0},{0,0,0,0},{0,0,0,0}};
            float4 qa[2][2], qb[2][8];
            #pragma unroll
            for (int j = 0; j < 2; ++j) {
                qa[j][0] = *(const float4*)(ap + j * 32);
                qa[j][1] = *(const float4*)(ap + j * 32 + 4);
                #pragma unroll
                for (int k = 0; k < 4; ++k) {
                    qb[j][2*k]   = *(const float4*)(bp[k] + j * 32);
                    qb[j][2*k+1] = *(const float4*)(bp[k] + j * 32 + 4);
                }
            }
            #pragma unroll 2
            for (int s = 0; s < 16; ++s) {
                const int b = s & 1;
                bf16x8 ah, al; cvt8(qa[b][0], qa[b][1], ah, al);
                #pragma unroll
                for (int k = 0; k < 4; ++k) {
                    bf16x8 bh, bl; cvt8(qb[b][2*k], qb[b][2*k+1], bh, bl);
                    acc[k] = MFMA(ah, bh, acc[k]);
                    acc[k] = MFMA(al, bh, acc[k]);
                    acc[k] = MFMA(ah, bl, acc[k]);
                }
                if (s + 2 < 16) {
                    qa[b][0] = *(const float4*)(ap + (s+2) * 32);
                    qa[b][1] = *(const float4*)(ap + (s+2) * 32 + 4);
                    #pragma unroll
                    for (int k = 0; k < 4; ++k) {
                        qb[b][2*k]   = *(const float4*)(bp[k] + (s+2) * 32);
                        qb[b][2*k+1] = *(const float4*)(bp[k] + (s+2) * 32 + 4);
                    }
                }
            }
            #pragma unroll
            for (int k = 0; k < 4; ++k)
                if (rv[k]) {
                    #pragma unroll
                    for (int i = 0; i < 4; ++i)
                        out[(size_t)(mt * 16 + q * 4 + i) * NOUT + col[k]]
                            = acc[k][i] + bias[k];
                }
        }
        return;
    }

    // ================= p_words: one (class, 16-row panel) per wave ===========
    const int wb0 = bid - (NSTR + NCB);   // (NSTR+NCB)%8==0 -> XCD = wb0&7
    // XCD-contiguous bijective remap (m204): XCD k gets a CONTIGUOUS wbid
    // range -> each XCD's CUs sweep one contiguous ~12.8 MB Ww region that
    // its own streamers are warming ahead of it.
    const int xcd  = wb0 & 7;
    const int slot = wb0 >> 3;
    const int base = (xcd < 2) ? xcd * 407 : 2 * 407 + (xcd - 2) * 406;
    const int wb   = base + slot;

    const int c = wb / NPAN;
    const int p = wb - c * NPAN;

    const int r  = p * 16 + n;
    const int rr = r < CHUNK ? r : CHUNK - 1;   // clamp pad rows (store-masked)

    // ---- load cls_idx + bias FIRST and pin them, so NO compiler waitcnt
    //      after this point can force a drain of the DMA queue ----
    int myvals[32];
    #pragma unroll
    for (int it = 0; it < 8; ++it) {
        int4 v = *(const int4*)&cls_idx[it * 256 + lane * 4];
        myvals[it*4+0] = v.x; myvals[it*4+1] = v.y;
        myvals[it*4+2] = v.z; myvals[it*4+3] = v.w;
    }
    float bias = bw[c * CHUNK + rr];
    #pragma unroll
    for (int it = 0; it < 8; ++it)
        asm volatile("" :: "v"(myvals[it*4]), "v"(myvals[it*4+1]),
                           "v"(myvals[it*4+2]), "v"(myvals[it*4+3]));
    asm volatile("" :: "v"(bias));

    // ---- DMA the whole 32 KB B panel, source-side XOR swizzle ----
    #pragma unroll
    for (int j = 0; j < 16; ++j) {
        int rj = p * 16 + j; if (rj > CHUNK - 1) rj = CHUNK - 1;
        const float* srow = Ww + ((size_t)c * CHUNK + rj) * NHID;
        const int lsw = (lane ^ (j & 7)) << 2;
        async16(srow + lsw,       &Bbuf[j * 512]);
        async16(srow + 256 + lsw, &Bbuf[j * 512 + 256]);
    }

    // ---- token membership scan (pure VALU now; overlaps DMA flight) ----
    int cnt = 0;
    #pragma unroll
    for (int j = 0; j < 32; ++j) {
        int idx  = (j >> 2) * 256 + lane * 4 + (j & 3);
        bool hit = (myvals[j] == c);
        unsigned long long m = __ballot(hit);
        if (hit) {
            int pos = cnt + (int)__popcll(m & ((1ull << lane) - 1ull));
            if (pos < MAXTOK) toktmp[pos] = idx;
        }
        cnt += (int)__popcll(m);
    }
    if (cnt == 0) {   // empty class: must drain DMA before LDS is reassigned
        asm volatile("s_waitcnt vmcnt(0)" ::: "memory");
        return;
    }
    const int cntc = cnt < MAXTOK ? cnt : MAXTOK;
    lds_fence_wave();

    // swizzled per-lane read bases: two 16B slots per k-step
    const float* Bb0 = Bbuf + n * 512 + (((q * 8))     ^ ((n & 7) << 2));
    const float* Bb1 = Bbuf + n * 512 + (((q * 8) + 4) ^ ((n & 7) << 2));

    // ---- token-slot groups (almost always exactly one: mean cnt = 8.2) ----
    for (int sb = 0; sb < cntc; sb += 16) {
        int slotn = sb + n;
        int mytok = toktmp[slotn < cntc ? slotn : 0];
        int tkS[4]; bool msk[4];
        #pragma unroll
        for (int i = 0; i < 4; ++i) {
            int m = q * 4 + i;
            tkS[i] = __shfl(mytok, m);
            msk[i] = (sb + m) < cntc;
        }
        const float* apx = x + (size_t)mytok * NHID + q * 8;

        // A chunks 0,1 direct-to-register (8 loads, newer than the 32 DMA)
        float4 pa[2][4];
        #pragma unroll
        for (int j = 0; j < 2; ++j)
            #pragma unroll
            for (int t = 0; t < 2; ++t) {
                pa[j][2*t]   = *(const float4*)(apx + (2*j + t) * 32);
                pa[j][2*t+1] = *(const float4*)(apx + (2*j + t) * 32 + 4);
            }
        // in-order retirement: <=8 outstanding left => all 32 DMA landed
        asm volatile("s_waitcnt vmcnt(8)" ::: "memory");

        f32x4 acc = {0.f, 0.f, 0.f, 0.f};
        #pragma unroll
        for (int j = 0; j < 8; ++j) {          // 8 chunks x 2 k-steps
            const int b = j & 1;
            #pragma unroll
            for (int t = 0; t < 2; ++t) {
                const int s = 2 * j + t;
                bf16x8 ah, al, bh, bl;
                cvt8(pa[b][2*t], pa[b][2*t+1], ah, al);
                float4 b0 = *(const float4*)(Bb0 + BOFF(s));
                float4 b1 = *(const float4*)(Bb1 + BOFF(s));
                cvt8(b0, b1, bh, bl);
                acc = MFMA(ah, bh, acc);
                acc = MFMA(al, bh, acc);
                acc = MFMA(ah, bl, acc);
            }
            if (j + 2 < 8) {                   // refill buffer b with chunk j+2
                #pragma unroll
                for (int t = 0; t < 2; ++t) {
                    const int s = 2 * (j + 2) + t;
                    pa[b][2*t]   = *(const float4*)(apx + s * 32);
                    pa[b][2*t+1] = *(const float4*)(apx + s * 32 + 4);
                }
            }
        }

        if (r < CHUNK) {
            #pragma unroll
            for (int i = 0; i < 4; ++i)
                if (msk[i])
                    out[(size_t)tkS[i] * NOUT + NCLS + r] = acc[i] + bias;
        }
    }
}

extern "C" void kernel_launch(void* const* d_in, const int* in_sizes, int n_in,
                              void* d_out, int out_size, void* d_ws, size_t ws_size,
                              hipStream_t stream) {
    const float* x   = (const float*)d_in[0];
    const float* Wc  = (const float*)d_in[1];
    const float* bc  = (const float*)d_in[2];
    const float* Ww  = (const float*)d_in[3];
    const float* bw  = (const float*)d_in[4];
    const int*   cls = (const int*)d_in[5];
    float* out = (float*)d_out;
    hipLaunchKernelGGL(cbd_fused, dim3(NBLK), dim3(NTHR), 0, stream,
                       x, Wc, bc, Ww, bw, cls, out);
}